// Round 7
// baseline (591.657 us; speedup 1.0000x reference)
//
#include <hip/hip_runtime.h>
#include <math.h>

typedef __bf16 bf16x8 __attribute__((ext_vector_type(8)));
typedef __bf16 bf16x4 __attribute__((ext_vector_type(4)));
typedef float  f32x4  __attribute__((ext_vector_type(4)));

// N=2, Q=1600, K=100, C=256, h=8, d=32.
// v7: fused bias+attn, 256 thr, Qb=1, barrier-free GEMM1 (pe gen in regs).
// ---- workspace layout (float offsets), total 737,312 f32 = 2.95 MB ----
#define WS_KH    0u        // [200][256] f32 k projection            -> 51200
#define WS_VH    51200u    // [200][256] f32 v projection            -> 102400
#define WS_EWTB  102400u   // bf16 [258][256] embed_w^T [j][c]       -> 135424
#define WS_OWTB  135424u   // bf16 [256][256] out_w^T [j][c]         -> 168192
#define WS_QHB   168192u   // bf16 [3200][256] scaled q projection   -> 577792
#define WS_KEB   577792u   // bf16 [200][264] key sin/cos (pad 264)  -> 604192
#define WS_W1B   604192u   // bf16 [256][256] pos_w1                 -> 636960
#define WS_W2PB  636960u   // bf16 [16][256] pos_w2 padded           -> 639008
#define WS_IPWT  639008u   // bf16 [256][768] in_proj_w^T            -> 737312

__device__ __forceinline__ float rdlane(float v, int l) {
  return __uint_as_float(__builtin_amdgcn_readlane(__float_as_uint(v), l));
}

// ---------------------------------------------------------------------------
// prep1: keb table, bf16 casts, weight transposes (LDS tiles)
__global__ __launch_bounds__(256) void prep1_kernel(
    const float* __restrict__ kpos,
    const float* __restrict__ pos_w1, const float* __restrict__ pos_w2,
    const float* __restrict__ embed_w, const float* __restrict__ out_w,
    const float* __restrict__ ipw, float* __restrict__ ws)
{
  __shared__ float tile[64 * 65];
  int bid = blockIdx.x, t = threadIdx.x;

  if (bid < 50) {
    int r = bid * 4 + (t >> 6);
    int u = t & 63;
    float p0 = kpos[r * 2 + 0], p1 = kpos[r * 2 + 1];
    __bf16* keb = (__bf16*)(ws + WS_KEB);
    bf16x4 o;
#pragma unroll
    for (int j = 0; j < 4; j++) {
      int col = u * 4 + j;
      int c = col >> 7, i = (col & 127) >> 1;
      float p = c ? p1 : p0;
      float inv = exp2f((float)i * (-13.287712379549449f / 64.0f));
      float v = p * inv;
      o[j] = (__bf16)((col & 1) ? __cosf(v) : __sinf(v));
    }
    *(bf16x4*)(keb + r * 264 + u * 4) = o;
  } else if (bid < 114) {
    int idx = (bid - 50) * 1024 + t * 4;
    float4 v = *(const float4*)(pos_w1 + idx);
    bf16x4 o; o[0] = (__bf16)v.x; o[1] = (__bf16)v.y; o[2] = (__bf16)v.z; o[3] = (__bf16)v.w;
    *(bf16x4*)((__bf16*)(ws + WS_W1B) + idx) = o;
  } else if (bid == 114) {
    __bf16* w2pb = (__bf16*)(ws + WS_W2PB);
    for (int i = 0; i < 16; i++) {
      int idx = t * 16 + i;
      w2pb[idx] = (idx < 2048) ? (__bf16)pos_w2[idx] : (__bf16)0.0f;
    }
  } else if (bid < 135) {
    // EWTB: embed_w [256 c][258 j] -> bf16 [j][c]
    int idx = bid - 115;
    int j0 = (idx / 4) * 64, c0 = (idx % 4) * 64;
    int jj = t & 63, rq = t >> 6;
    for (int rr = 0; rr < 16; rr++) {
      int c = rr * 4 + rq;
      float v = (j0 + jj < 258) ? embed_w[(c0 + c) * 258 + j0 + jj] : 0.0f;
      tile[c * 65 + jj] = v;
    }
    __syncthreads();
    __bf16* ewtb = (__bf16*)(ws + WS_EWTB);
    int cc = t & 63, jq = t >> 6;
    for (int pp = 0; pp < 16; pp++) {
      int j = pp * 4 + jq;
      if (j0 + j < 258)
        ewtb[(unsigned)(j0 + j) * 256u + c0 + cc] = (__bf16)tile[cc * 65 + j];
    }
  } else if (bid < 151) {
    // OWTB: out_w [256 c][256 j] -> bf16 [j][c]
    int idx = bid - 135;
    int j0 = (idx >> 2) * 64, c0 = (idx & 3) * 64;
    int jj = t & 63, rq = t >> 6;
    for (int rr = 0; rr < 16; rr++) {
      int c = rr * 4 + rq;
      tile[c * 65 + jj] = out_w[(c0 + c) * 256 + j0 + jj];
    }
    __syncthreads();
    __bf16* owtb = (__bf16*)(ws + WS_OWTB);
    int cc = t & 63, jq = t >> 6;
    for (int pp = 0; pp < 16; pp++) {
      int j = pp * 4 + jq;
      owtb[(unsigned)(j0 + j) * 256u + c0 + cc] = (__bf16)tile[cc * 65 + j];
    }
  } else {
    // IPWT: ipw [768 o][256 j] -> bf16 [j][768 o]
    int idx = bid - 151;                 // 48 blocks
    int j0 = (idx & 3) * 64, o0 = (idx >> 2) * 64;
    int jj = t & 63, rq = t >> 6;
    for (int rr = 0; rr < 16; rr++) {
      int o = rr * 4 + rq;
      tile[o * 65 + jj] = ipw[(unsigned)(o0 + o) * 256u + j0 + jj];
    }
    __syncthreads();
    __bf16* ipwt = (__bf16*)(ws + WS_IPWT);
    int oo = t & 63, jq = t >> 6;
    for (int pp = 0; pp < 16; pp++) {
      int j = pp * 4 + jq;
      ipwt[(unsigned)(j0 + j) * 768u + o0 + oo] = (__bf16)tile[oo * 65 + j];
    }
  }
}

// ---------------------------------------------------------------------------
// prep2: q/k/v projections (coalesced transposed-weight reads)
__global__ __launch_bounds__(256, 2) void prep2_kernel(
    const float* __restrict__ qfeat, const float* __restrict__ kfeat,
    const float* __restrict__ ipb, float* __restrict__ ws)
{
  __shared__ float x[8 * 256];
  int bid = blockIdx.x, t = threadIdx.x;
  const __bf16* ipwt = (const __bf16*)(ws + WS_IPWT);

  if (bid < 400) {
    int r0 = bid * 8;
    for (int i = t; i < 2048; i += 256) x[i] = qfeat[(unsigned)r0 * 256u + i];
    __syncthreads();
    float acc[8]; float bq = ipb[t];
#pragma unroll
    for (int rr = 0; rr < 8; rr++) acc[rr] = bq;
#pragma unroll 4
    for (int j = 0; j < 256; j += 4) {
      float w0 = (float)ipwt[(unsigned)(j + 0) * 768u + t];
      float w1 = (float)ipwt[(unsigned)(j + 1) * 768u + t];
      float w2 = (float)ipwt[(unsigned)(j + 2) * 768u + t];
      float w3 = (float)ipwt[(unsigned)(j + 3) * 768u + t];
#pragma unroll
      for (int rr = 0; rr < 8; rr++) {
        float4 x4 = *(const float4*)(x + rr * 256 + j);
        acc[rr] = fmaf(x4.x, w0, fmaf(x4.y, w1, fmaf(x4.z, w2, fmaf(x4.w, w3, acc[rr]))));
      }
    }
    __bf16* qhb = (__bf16*)(ws + WS_QHB);
#pragma unroll
    for (int rr = 0; rr < 8; rr++)
      qhb[(unsigned)(r0 + rr) * 256u + t] = (__bf16)(acc[rr] * 0.17677669529663687f);
  } else {
    int b2 = bid - 400; int n = b2 >> 4, tileI = b2 & 15;
    int r0l = tileI * 7; int cnt = 100 - r0l; if (cnt > 7) cnt = 7; if (cnt <= 0) return;
    int r0 = n * 100 + r0l;
    for (int i = t; i < cnt * 256; i += 256) x[i] = kfeat[(unsigned)r0 * 256u + i];
    __syncthreads();
    float ak[7], av[7]; float bk = ipb[256 + t], bv = ipb[512 + t];
#pragma unroll
    for (int rr = 0; rr < 7; rr++) { ak[rr] = bk; av[rr] = bv; }
#pragma unroll 2
    for (int j = 0; j < 256; j += 4) {
      float wk0 = (float)ipwt[(unsigned)(j + 0) * 768u + 256 + t];
      float wk1 = (float)ipwt[(unsigned)(j + 1) * 768u + 256 + t];
      float wk2 = (float)ipwt[(unsigned)(j + 2) * 768u + 256 + t];
      float wk3 = (float)ipwt[(unsigned)(j + 3) * 768u + 256 + t];
      float wv0 = (float)ipwt[(unsigned)(j + 0) * 768u + 512 + t];
      float wv1 = (float)ipwt[(unsigned)(j + 1) * 768u + 512 + t];
      float wv2 = (float)ipwt[(unsigned)(j + 2) * 768u + 512 + t];
      float wv3 = (float)ipwt[(unsigned)(j + 3) * 768u + 512 + t];
#pragma unroll
      for (int rr = 0; rr < 7; rr++) {
        float4 x4 = *(const float4*)(x + rr * 256 + j);
        ak[rr] = fmaf(x4.x, wk0, fmaf(x4.y, wk1, fmaf(x4.z, wk2, fmaf(x4.w, wk3, ak[rr]))));
        av[rr] = fmaf(x4.x, wv0, fmaf(x4.y, wv1, fmaf(x4.z, wv2, fmaf(x4.w, wv3, av[rr]))));
      }
    }
    for (int rr = 0; rr < 7; rr++) {
      if (rr < cnt) {
        ws[WS_KH + (unsigned)(r0 + rr) * 256u + t] = ak[rr];
        ws[WS_VH + (unsigned)(r0 + rr) * 256u + t] = av[rr];
      }
    }
  }
}

// ---------------------------------------------------------------------------
// fused kernel: 1 query/block, 256 threads (4 waves), grid 3200.
// GEMM1 (barrier-free): wave w owns c in [64w,64w+64) (4 ctiles) x 7 keytiles.
// A = W1 frags streamed from L2; B = pe generated IN REGISTERS per lane
// (lane (quad,l15) of (kc,mt) is exactly B[k=quad*8+j][n=key=mt*16+l15]).
// GEMM2: region exchange (4 slots, 2 rounds, row-XOR swizzle), bias -> attn_s.
// Then attention + epilogues in-block.
// LDS: qe 512 @0 | region 32768 @512 | attn_s 3328 @33280 | qh_s 1152 @36608
//      | ctx 1024 @37760 | cat 1056 @38784 | aw 416 @39840  (= 40256 B)
__global__ __launch_bounds__(256) void fused_kernel(
    const float* __restrict__ qpos, const float* __restrict__ kpos,
    const float* __restrict__ qfeat,
    const float* __restrict__ pos_b1, const float* __restrict__ pos_b2,
    const float* __restrict__ out_b, const float* __restrict__ embed_b,
    const float* __restrict__ ptw,
    const float* __restrict__ ws, float* __restrict__ out)
{
  __shared__ __align__(16) char smem[40256];
  __bf16* qe_s   = (__bf16*)smem;
  __bf16* region = (__bf16*)(smem + 512);
  float* attn_s  = (float*)(smem + 33280);   // [8][104]
  float* qh_s    = (float*)(smem + 36608);   // [8][36]
  float* ctx_s   = (float*)(smem + 37760);   // [256]
  float* cat_s   = (float*)(smem + 38784);   // [264]
  float* aw_s    = (float*)(smem + 39840);   // [104]

  int q = blockIdx.x;              // 0..3199
  int n = q >> 11 ? 1 : (q >= 1600 ? 1 : 0);
  n = (q >= 1600) ? 1 : 0;
  int t = threadIdx.x;
  int lane = t & 63, w = t >> 6;
  int l15 = lane & 15, quad = lane >> 4;

  const __bf16* keb  = (const __bf16*)(ws + WS_KEB) + (unsigned)(n * 100) * 264u;
  const __bf16* w1b  = (const __bf16*)(ws + WS_W1B);
  const __bf16* w2pb = (const __bf16*)(ws + WS_W2PB);
  const __bf16* qhb  = (const __bf16*)(ws + WS_QHB);
  const float* kh = ws + WS_KH;
  const float* vh = ws + WS_VH;
  const __bf16* owtb = (const __bf16*)(ws + WS_OWTB);
  const __bf16* ewtb = (const __bf16*)(ws + WS_EWTB);

  // qe table for this query: thread t computes one sin or cos
  {
    int c = t >> 7, i = (t & 127) >> 1;
    float p = qpos[q * 2 + c];
    float inv = exp2f((float)i * (-13.287712379549449f / 64.0f));
    float v = p * inv;
    qe_s[t] = (__bf16)((t & 1) ? __cosf(v) : __sinf(v));
  }

  float b1v[4][4];
#pragma unroll
  for (int ct = 0; ct < 4; ct++)
#pragma unroll
    for (int r = 0; r < 4; r++) b1v[ct][r] = pos_b1[w * 64 + ct * 16 + quad * 4 + r];
  float b2v[4];
#pragma unroll
  for (int r = 0; r < 4; r++) b2v[r] = pos_b2[(quad * 4 + r) & 7];

  f32x4 zero4; zero4[0] = 0.f; zero4[1] = 0.f; zero4[2] = 0.f; zero4[3] = 0.f;
  f32x4 acc[4][7];
#pragma unroll
  for (int ct = 0; ct < 4; ct++)
#pragma unroll
    for (int mt = 0; mt < 7; mt++) acc[ct][mt] = zero4;

  __syncthreads();   // qe_s ready

  // ---- GEMM1: D1[c][key] = sum_k W1[c][k]*pe[key][k] — no barriers ----
  const __bf16* w1r = w1b + (unsigned)(w * 64 + l15) * 256u + quad * 8;
  for (int kc = 0; kc < 8; kc++) {
    bf16x8 wf[4];
#pragma unroll
    for (int ct = 0; ct < 4; ct++)
      wf[ct] = *(const bf16x8*)(w1r + (unsigned)(ct * 16) * 256u + kc * 32);
    bf16x8 qf = *(const bf16x8*)(qe_s + kc * 32 + quad * 8);
    const __bf16* kebk = keb + kc * 32 + quad * 8;
#pragma unroll
    for (int mt = 0; mt < 7; mt++) {
      int key = mt * 16 + l15;
      bf16x8 bfr;
      if (key < 100) {
        bf16x8 kf = *(const bf16x8*)(kebk + (unsigned)key * 264u);
#pragma unroll
        for (int pp = 0; pp < 4; pp++) {
          float sk = (float)kf[2 * pp], ck = (float)kf[2 * pp + 1];
          float sq = (float)qf[2 * pp], cq = (float)qf[2 * pp + 1];
          bfr[2 * pp]     = (__bf16)(sk * cq - ck * sq);
          bfr[2 * pp + 1] = (__bf16)(ck * cq + sk * sq);
        }
      } else {
#pragma unroll
        for (int jj = 0; jj < 8; jj++) bfr[jj] = (__bf16)0.f;
      }
#pragma unroll
      for (int ct = 0; ct < 4; ct++)
        acc[ct][mt] = __builtin_amdgcn_mfma_f32_16x16x32_bf16(wf[ct], bfr, acc[ct][mt], 0, 0, 0);
    }
  }

  // hid = relu(D1 + b1)  (lane: c = 64w + ct*16 + quad*4 + r, key = mt*16+l15)
#pragma unroll
  for (int ct = 0; ct < 4; ct++)
#pragma unroll
    for (int mt = 0; mt < 7; mt++)
#pragma unroll
      for (int r = 0; r < 4; r++)
        acc[ct][mt][r] = fmaxf(acc[ct][mt][r] + b1v[ct][r], 0.0f);

  // ---- GEMM2: region exchange + MFMA vs w2; bias straight into attn_s ----
  auto swz = [](int row) { return row ^ ((row >> 4) & 7); };
  auto wreg = [&](int mt, int slot) {
#pragma unroll
    for (int ct = 0; ct < 4; ct++) {
      int row = (2 * w + (ct >> 1)) * 64 + ((ct & 1) * 2 + (quad >> 1)) * 16 + l15;
      int r2 = swz(row);
      bf16x4 o;
#pragma unroll
      for (int r = 0; r < 4; r++) o[r] = (__bf16)acc[ct][mt][r];
      *(bf16x4*)(region + slot * 4096 + r2 * 8 + (quad & 1) * 4) = o;
    }
  };
  auto g2 = [&](int mt, int slot) {
    f32x4 acc2 = zero4;
    const __bf16* rg = region + slot * 4096;
#pragma unroll
    for (int s = 0; s < 8; s++) {
      bf16x8 w2f = *(const bf16x8*)(w2pb + (unsigned)l15 * 256u + s * 32 + quad * 8);
      int row = s * 64 + lane;
      bf16x8 hf = *(const bf16x8*)(rg + swz(row) * 8);
      acc2 = __builtin_amdgcn_mfma_f32_16x16x32_bf16(w2f, hf, acc2, 0, 0, 0);
    }
    if (quad < 2) {
      int key = mt * 16 + l15;
      if (key < 100) {
#pragma unroll
        for (int r = 0; r < 4; r++)
          attn_s[(quad * 4 + r) * 104 + key] = acc2[r] + b2v[r];
      }
    }
  };

  wreg(0, 0); wreg(1, 1); wreg(2, 2); wreg(3, 3);
  __syncthreads();
  g2(w, w);                          // all 4 waves: mt 0-3
  __syncthreads();
  wreg(4, 0); wreg(5, 1); wreg(6, 2);
  __syncthreads();
  if (w < 3) {
    g2(4 + w, w);                    // mt 4-6
  } else {
    // wave 3: load qh into LDS (f32, [h][36] padded)
    bf16x4 v4 = *(const bf16x4*)(qhb + (unsigned)q * 256u + lane * 4);
    int c = lane * 4;
    float* dst = qh_s + (c >> 5) * 36 + (c & 31);
    dst[0] = (float)v4[0]; dst[1] = (float)v4[1];
    dst[2] = (float)v4[2]; dst[3] = (float)v4[3];
  }
  __syncthreads();

  // ---- attention: scores += qh.kh ----
#pragma unroll
  for (int i = 0; i < 4; i++) {
    int p = t + i * 256;
    if (p < 800) {
      int k = p >> 3, h = p & 7;
      const float4* kf4 = (const float4*)(kh + (unsigned)(n * 100 + k) * 256u + h * 32);
      const float4* qf4 = (const float4*)(qh_s + h * 36);
      float s = attn_s[h * 104 + k];
#pragma unroll
      for (int dd = 0; dd < 8; dd++) {
        float4 kv = kf4[dd], qv = qf4[dd];
        s += kv.x * qv.x + kv.y * qv.y + kv.z * qv.z + kv.w * qv.w;
      }
      attn_s[h * 104 + k] = s;
    }
  }
  __syncthreads();

  // softmax: 8 rows x 32 lanes
  {
    int h = t >> 5, j = t & 31;
    float* row = attn_s + h * 104;
    float mx = -1e30f;
    for (int k = j; k < 100; k += 32) mx = fmaxf(mx, row[k]);
    mx = fmaxf(mx, __shfl_xor(mx, 1, 32));
    mx = fmaxf(mx, __shfl_xor(mx, 2, 32));
    mx = fmaxf(mx, __shfl_xor(mx, 4, 32));
    mx = fmaxf(mx, __shfl_xor(mx, 8, 32));
    mx = fmaxf(mx, __shfl_xor(mx, 16, 32));
    float sum = 0.f;
    for (int k = j; k < 100; k += 32) { float e = __expf(row[k] - mx); row[k] = e; sum += e; }
    sum += __shfl_xor(sum, 1, 32);
    sum += __shfl_xor(sum, 2, 32);
    sum += __shfl_xor(sum, 4, 32);
    sum += __shfl_xor(sum, 8, 32);
    sum += __shfl_xor(sum, 16, 32);
    float inv = 1.0f / sum;
    for (int k = j; k < 100; k += 32) row[k] *= inv;
  }
  __syncthreads();

  // aw = mean over heads; ctx = attn @ vh
  if (t < 100) {
    float s = 0.f;
#pragma unroll
    for (int h = 0; h < 8; h++) s += attn_s[h * 104 + t];
    aw_s[t] = s * 0.125f;
  }
  {
    int c = t, h = c >> 5;
    float a = 0.f;
    const float* vp = vh + (unsigned)(n * 100) * 256u + c;
    const float* rw = attn_s + h * 104;
#pragma unroll 4
    for (int k = 0; k < 100; k++)
      a = fmaf(rw[k], vp[(unsigned)k * 256u], a);
    ctx_s[c] = a;
  }
  __syncthreads();

  // cat extras (new_pos)
  if (t < 2) {
    int cd = t;
    float qp = qpos[q * 2 + cd];
    float s = 0.f;
    for (int k = 0; k < 100; k++)
      s = fmaf(aw_s[k], kpos[(n * 100 + k) * 2 + cd] - qp, s);
    float so = __shfl_xor(s, 1, 2);
    if (cd == 0) cat_s[256] = ptw[0] * s + ptw[1] * so;
    else         cat_s[257] = ptw[2] * so + ptw[3] * s;
  }

  // out_proj (coalesced bf16 weights, ctx broadcast via readlane)
  {
    int c = t;
    float acc0 = out_b[c];
    for (int ch = 0; ch < 4; ch++) {
      float v0 = ctx_s[ch * 64 + lane];
      const __bf16* wp = owtb + (unsigned)(ch * 64) * 256u + c;
#pragma unroll 8
      for (int j2 = 0; j2 < 64; j2++) {
        float wv = (float)wp[(unsigned)j2 * 256u];
        acc0 = fmaf(rdlane(v0, j2), wv, acc0);
      }
    }
    cat_s[c] = fmaxf(qfeat[(unsigned)q * 256u + c] + acc0, 0.f);
  }
  __syncthreads();

  // embed (rows 256/257 = new_pos)
  {
    int c = t;
    float acc0 = embed_b[c];
    for (int ch = 0; ch < 4; ch++) {
      float v0 = cat_s[ch * 64 + lane];
      const __bf16* wp = ewtb + (unsigned)(ch * 64) * 256u + c;
#pragma unroll 8
      for (int j2 = 0; j2 < 64; j2++) {
        float wv = (float)wp[(unsigned)j2 * 256u];
        acc0 = fmaf(rdlane(v0, j2), wv, acc0);
      }
    }
    float w256 = (float)ewtb[256u * 256u + c];
    float w257 = (float)ewtb[257u * 256u + c];
    acc0 += cat_s[256] * w256 + cat_s[257] * w257;
    out[(unsigned)q * 256u + c] = fmaxf(acc0, 0.f);
  }
}

// ---------------------------------------------------------------------------
extern "C" void kernel_launch(void* const* d_in, const int* in_sizes, int n_in,
                              void* d_out, int out_size, void* d_ws, size_t ws_size,
                              hipStream_t stream)
{
  const float* query_feature  = (const float*)d_in[0];
  const float* query_position = (const float*)d_in[1];
  const float* key_feature    = (const float*)d_in[2];
  const float* key_position   = (const float*)d_in[3];
  const float* in_proj_w      = (const float*)d_in[4];
  const float* in_proj_b      = (const float*)d_in[5];
  const float* out_proj_w     = (const float*)d_in[6];
  const float* out_proj_b     = (const float*)d_in[7];
  const float* pos_w1         = (const float*)d_in[8];
  const float* pos_b1         = (const float*)d_in[9];
  const float* pos_w2         = (const float*)d_in[10];
  const float* pos_b2         = (const float*)d_in[11];
  const float* pos_trans_w    = (const float*)d_in[12];
  const float* embed_w        = (const float*)d_in[13];
  const float* embed_b        = (const float*)d_in[14];
  float* ws  = (float*)d_ws;
  float* out = (float*)d_out;

  hipLaunchKernelGGL(prep1_kernel, dim3(199), dim3(256), 0, stream,
                     key_position, pos_w1, pos_w2, embed_w, out_proj_w,
                     in_proj_w, ws);
  hipLaunchKernelGGL(prep2_kernel, dim3(432), dim3(256), 0, stream,
                     query_feature, key_feature, in_proj_b, ws);
  hipLaunchKernelGGL(fused_kernel, dim3(3200), dim3(256), 0, stream,
                     query_position, key_position, query_feature,
                     pos_b1, pos_b2, out_proj_b, embed_b, pos_trans_w,
                     ws, out);
}

// Round 8
// 400.977 us; speedup vs baseline: 1.4755x; 1.4755x over previous
//
#include <hip/hip_runtime.h>
#include <math.h>

typedef __bf16 bf16x8 __attribute__((ext_vector_type(8)));
typedef __bf16 bf16x4 __attribute__((ext_vector_type(4)));
typedef float  f32x4  __attribute__((ext_vector_type(4)));

// N=2, Q=1600, K=100, C=256, h=8, d=32.
// v8: bias+attn fused (Qb=2, 512 thr, grid 1600); prep2 register-broadcast.
// ---- workspace layout (float offsets), total 737,312 f32 = 2.95 MB ----
#define WS_KH    0u        // [200][256] f32 k projection            -> 51200
#define WS_VH    51200u    // [200][256] f32 v projection            -> 102400
#define WS_EWTB  102400u   // bf16 [258][256] embed_w^T [j][c]       -> 135424
#define WS_OWTB  135424u   // bf16 [256][256] out_w^T [j][c]         -> 168192
#define WS_QHB   168192u   // bf16 [3200][256] scaled q projection   -> 577792
#define WS_KEB   577792u   // bf16 [200][264] key sin/cos (pad 264)  -> 604192
#define WS_W1B   604192u   // bf16 [256][256] pos_w1                 -> 636960
#define WS_W2PB  636960u   // bf16 [16][256] pos_w2 padded           -> 639008
#define WS_IPWT  639008u   // bf16 [256][768] in_proj_w^T            -> 737312

__device__ __forceinline__ float rdlane(float v, int l) {
  return __uint_as_float(__builtin_amdgcn_readlane(__float_as_uint(v), l));
}

// ---------------------------------------------------------------------------
// prep1: keb table, bf16 casts, weight transposes (LDS tiles)
__global__ __launch_bounds__(256) void prep1_kernel(
    const float* __restrict__ kpos,
    const float* __restrict__ pos_w1, const float* __restrict__ pos_w2,
    const float* __restrict__ embed_w, const float* __restrict__ out_w,
    const float* __restrict__ ipw, float* __restrict__ ws)
{
  __shared__ float tile[64 * 65];
  int bid = blockIdx.x, t = threadIdx.x;

  if (bid < 50) {
    int r = bid * 4 + (t >> 6);
    int u = t & 63;
    float p0 = kpos[r * 2 + 0], p1 = kpos[r * 2 + 1];
    __bf16* keb = (__bf16*)(ws + WS_KEB);
    bf16x4 o;
#pragma unroll
    for (int j = 0; j < 4; j++) {
      int col = u * 4 + j;
      int c = col >> 7, i = (col & 127) >> 1;
      float p = c ? p1 : p0;
      float inv = exp2f((float)i * (-13.287712379549449f / 64.0f));
      float v = p * inv;
      o[j] = (__bf16)((col & 1) ? __cosf(v) : __sinf(v));
    }
    *(bf16x4*)(keb + r * 264 + u * 4) = o;
  } else if (bid < 114) {
    int idx = (bid - 50) * 1024 + t * 4;
    float4 v = *(const float4*)(pos_w1 + idx);
    bf16x4 o; o[0] = (__bf16)v.x; o[1] = (__bf16)v.y; o[2] = (__bf16)v.z; o[3] = (__bf16)v.w;
    *(bf16x4*)((__bf16*)(ws + WS_W1B) + idx) = o;
  } else if (bid == 114) {
    __bf16* w2pb = (__bf16*)(ws + WS_W2PB);
    for (int i = 0; i < 16; i++) {
      int idx = t * 16 + i;
      w2pb[idx] = (idx < 2048) ? (__bf16)pos_w2[idx] : (__bf16)0.0f;
    }
  } else if (bid < 135) {
    // EWTB: embed_w [256 c][258 j] -> bf16 [j][c]
    int idx = bid - 115;
    int j0 = (idx / 4) * 64, c0 = (idx % 4) * 64;
    int jj = t & 63, rq = t >> 6;
    for (int rr = 0; rr < 16; rr++) {
      int c = rr * 4 + rq;
      float v = (j0 + jj < 258) ? embed_w[(c0 + c) * 258 + j0 + jj] : 0.0f;
      tile[c * 65 + jj] = v;
    }
    __syncthreads();
    __bf16* ewtb = (__bf16*)(ws + WS_EWTB);
    int cc = t & 63, jq = t >> 6;
    for (int pp = 0; pp < 16; pp++) {
      int j = pp * 4 + jq;
      if (j0 + j < 258)
        ewtb[(unsigned)(j0 + j) * 256u + c0 + cc] = (__bf16)tile[cc * 65 + j];
    }
  } else if (bid < 151) {
    // OWTB: out_w [256 c][256 j] -> bf16 [j][c]
    int idx = bid - 135;
    int j0 = (idx >> 2) * 64, c0 = (idx & 3) * 64;
    int jj = t & 63, rq = t >> 6;
    for (int rr = 0; rr < 16; rr++) {
      int c = rr * 4 + rq;
      tile[c * 65 + jj] = out_w[(c0 + c) * 256 + j0 + jj];
    }
    __syncthreads();
    __bf16* owtb = (__bf16*)(ws + WS_OWTB);
    int cc = t & 63, jq = t >> 6;
    for (int pp = 0; pp < 16; pp++) {
      int j = pp * 4 + jq;
      owtb[(unsigned)(j0 + j) * 256u + c0 + cc] = (__bf16)tile[cc * 65 + j];
    }
  } else {
    // IPWT: ipw [768 o][256 j] -> bf16 [j][768 o]
    int idx = bid - 151;                 // 48 blocks
    int j0 = (idx & 3) * 64, o0 = (idx >> 2) * 64;
    int jj = t & 63, rq = t >> 6;
    for (int rr = 0; rr < 16; rr++) {
      int o = rr * 4 + rq;
      tile[o * 65 + jj] = ipw[(unsigned)(o0 + o) * 256u + j0 + jj];
    }
    __syncthreads();
    __bf16* ipwt = (__bf16*)(ws + WS_IPWT);
    int oo = t & 63, jq = t >> 6;
    for (int pp = 0; pp < 16; pp++) {
      int j = pp * 4 + jq;
      ipwt[(unsigned)(j0 + j) * 768u + o0 + oo] = (__bf16)tile[oo * 65 + j];
    }
  }
}

// ---------------------------------------------------------------------------
// prep2: q/k/v projections — x rows in registers, broadcast via readlane.
// Zero LDS; weight reads coalesced bf16.
__global__ __launch_bounds__(256, 2) void prep2_kernel(
    const float* __restrict__ qfeat, const float* __restrict__ kfeat,
    const float* __restrict__ ipb, float* __restrict__ ws)
{
  int bid = blockIdx.x, t = threadIdx.x, lane = t & 63;
  const __bf16* ipwt = (const __bf16*)(ws + WS_IPWT);

  if (bid < 400) {
    int r0 = bid * 8;
    float xr[8][4];
#pragma unroll
    for (int rr = 0; rr < 8; rr++)
#pragma unroll
      for (int ch = 0; ch < 4; ch++)
        xr[rr][ch] = qfeat[(unsigned)(r0 + rr) * 256u + ch * 64 + lane];
    float acc[8]; float bq = ipb[t];
#pragma unroll
    for (int rr = 0; rr < 8; rr++) acc[rr] = bq;
#pragma unroll
    for (int ch = 0; ch < 4; ch++) {
#pragma unroll 8
      for (int j2 = 0; j2 < 64; j2++) {
        float wv = (float)ipwt[(unsigned)(ch * 64 + j2) * 768u + t];
#pragma unroll
        for (int rr = 0; rr < 8; rr++)
          acc[rr] = fmaf(rdlane(xr[rr][ch], j2), wv, acc[rr]);
      }
    }
    __bf16* qhb = (__bf16*)(ws + WS_QHB);
#pragma unroll
    for (int rr = 0; rr < 8; rr++)
      qhb[(unsigned)(r0 + rr) * 256u + t] = (__bf16)(acc[rr] * 0.17677669529663687f);
  } else {
    int b2 = bid - 400; int n = b2 >> 4, tileI = b2 & 15;
    int r0l = tileI * 7; int cnt = 100 - r0l; if (cnt > 7) cnt = 7; if (cnt <= 0) return;
    int r0 = n * 100 + r0l;
    float xr[7][4];
#pragma unroll
    for (int rr = 0; rr < 7; rr++)
#pragma unroll
      for (int ch = 0; ch < 4; ch++)
        xr[rr][ch] = (rr < cnt) ? kfeat[(unsigned)(r0 + rr) * 256u + ch * 64 + lane] : 0.0f;
    float ak[7], av[7]; float bk = ipb[256 + t], bv = ipb[512 + t];
#pragma unroll
    for (int rr = 0; rr < 7; rr++) { ak[rr] = bk; av[rr] = bv; }
#pragma unroll
    for (int ch = 0; ch < 4; ch++) {
#pragma unroll 4
      for (int j2 = 0; j2 < 64; j2++) {
        float wk = (float)ipwt[(unsigned)(ch * 64 + j2) * 768u + 256 + t];
        float wvv = (float)ipwt[(unsigned)(ch * 64 + j2) * 768u + 512 + t];
#pragma unroll
        for (int rr = 0; rr < 7; rr++) {
          float xb = rdlane(xr[rr][ch], j2);
          ak[rr] = fmaf(xb, wk, ak[rr]);
          av[rr] = fmaf(xb, wvv, av[rr]);
        }
      }
    }
    for (int rr = 0; rr < 7; rr++) {
      if (rr < cnt) {
        ws[WS_KH + (unsigned)(r0 + rr) * 256u + t] = ak[rr];
        ws[WS_VH + (unsigned)(r0 + rr) * 256u + t] = av[rr];
      }
    }
  }
}

// ---------------------------------------------------------------------------
// fused bias+attn: Qb=2, 512 threads (8 waves), grid 1600.
// GEMM1: round-6 structure (wave w owns c in [32w,32w+32); pe staged via a
// single LDS buffer, loads pipelined ahead of the MFMAs). GEMM2: 4-slot
// region exchange; bias lands in LDS. Phase 2: attention + epilogues,
// reusing the pe-buffer LDS.
// LDS: peA [896]x16B @0 (14336) | qe bf16[2][256] @14336 (1024)
//      | region 4x8192 @15360 (32768) | bias_s bf16[2][8][104] @48128 (3328)
//      = 51456. Phase-2 overlays: qh@0, ctx@2304, cat@4352, aw@6464,
//      scores f32[2][8][104] @15360.
__global__ __launch_bounds__(512) void fused_kernel(
    const float* __restrict__ qpos, const float* __restrict__ kpos,
    const float* __restrict__ qfeat,
    const float* __restrict__ pos_b1, const float* __restrict__ pos_b2,
    const float* __restrict__ out_b, const float* __restrict__ embed_b,
    const float* __restrict__ ptw,
    const float* __restrict__ ws, float* __restrict__ out)
{
  __shared__ __align__(16) char smem[51456];
  __bf16* qe_s   = (__bf16*)(smem + 14336);
  __bf16* region = (__bf16*)(smem + 15360);
  __bf16* bias_s = (__bf16*)(smem + 48128);
  float* qh_s   = (float*)smem;            // [2][8][36]
  float* ctx_s  = (float*)(smem + 2304);   // [2][256]
  float* cat_s  = (float*)(smem + 4352);   // [2][264]
  float* aw_s   = (float*)(smem + 6464);   // [2][104]
  float* scores = (float*)(smem + 15360);  // [2][8][104]

  int bid = blockIdx.x;            // 0..1599
  int n = (bid >= 800) ? 1 : 0;
  int q0 = bid * 2;
  int t = threadIdx.x;
  int lane = t & 63, w = t >> 6;
  int l15 = lane & 15, quad = lane >> 4;

  const __bf16* keb  = (const __bf16*)(ws + WS_KEB) + (unsigned)(n * 100) * 264u;
  const __bf16* w1b  = (const __bf16*)(ws + WS_W1B);
  const __bf16* w2pb = (const __bf16*)(ws + WS_W2PB);
  const __bf16* qhb  = (const __bf16*)(ws + WS_QHB);
  const __bf16* owtb = (const __bf16*)(ws + WS_OWTB);
  const __bf16* ewtb = (const __bf16*)(ws + WS_EWTB);
  const float* kh = ws + WS_KH;
  const float* vh = ws + WS_VH;

  // qe for the block's 2 queries: thread computes one sin or cos
  {
    int q = t >> 8, u = t & 255;
    int c = u >> 7, i = (u & 127) >> 1;
    float p = qpos[(q0 + q) * 2 + c];
    float inv = exp2f((float)i * (-13.287712379549449f / 64.0f));
    float v = p * inv;
    qe_s[q * 256 + u] = (__bf16)((u & 1) ? __cosf(v) : __sinf(v));
  }

  // W1 A-frags in registers: wave w owns c in [32w, 32w+32)
  bf16x8 wfrag[2][8];
#pragma unroll
  for (int ct = 0; ct < 2; ct++)
#pragma unroll
    for (int kc = 0; kc < 8; kc++)
      wfrag[ct][kc] = *(const bf16x8*)(w1b + (unsigned)(w * 32 + ct * 16 + l15) * 256u + kc * 32 + quad * 8);
  float b1v[2][4];
#pragma unroll
  for (int ct = 0; ct < 2; ct++)
#pragma unroll
    for (int r = 0; r < 4; r++) b1v[ct][r] = pos_b1[w * 32 + ct * 16 + quad * 4 + r];
  float b2v[4];
#pragma unroll
  for (int r = 0; r < 4; r++) b2v[r] = pos_b2[(quad * 4 + r) & 7];

  // pe generator (single buffer, loads pipelined ahead of MFMAs)
  bool gact = (t < 448);
  int gkey = t >> 2, gsub = t & 3;
  int gmt = gkey >> 4, gkl = gkey & 15;
  int gkcl = gsub >> 1, gqd0 = (gsub & 1) * 2;
  bf16x8 gk0, gk1, gq0, gq1;

  auto gen_load = [&](int q, int pair) {
    if (gact) {
      int cb = pair * 64 + gsub * 16;
      const __bf16* qp = qe_s + q * 256 + cb;
      gq0 = *(const bf16x8*)qp;
      gq1 = *(const bf16x8*)(qp + 8);
      if (gkey < 100) {
        const __bf16* kp = keb + (unsigned)gkey * 264u + cb;
        gk0 = *(const bf16x8*)kp;
        gk1 = *(const bf16x8*)(kp + 8);
      }
    }
  };
  auto gen_store = [&]() {
    if (gact) {
      bf16x8 fr0, fr1;
      if (gkey < 100) {
#pragma unroll
        for (int jj = 0; jj < 4; jj++) {
          float sk = (float)gk0[2 * jj], ck = (float)gk0[2 * jj + 1];
          float sq = (float)gq0[2 * jj], cq = (float)gq0[2 * jj + 1];
          fr0[2 * jj]     = (__bf16)(sk * cq - ck * sq);
          fr0[2 * jj + 1] = (__bf16)(ck * cq + sk * sq);
          float sk1 = (float)gk1[2 * jj], ck1 = (float)gk1[2 * jj + 1];
          float sq1 = (float)gq1[2 * jj], cq1 = (float)gq1[2 * jj + 1];
          fr1[2 * jj]     = (__bf16)(sk1 * cq1 - ck1 * sq1);
          fr1[2 * jj + 1] = (__bf16)(ck1 * cq1 + sk1 * sq1);
        }
      } else {
#pragma unroll
        for (int jj = 0; jj < 8; jj++) { fr0[jj] = (__bf16)0.f; fr1[jj] = (__bf16)0.f; }
      }
      bf16x8* base = (bf16x8*)smem + gkcl * 448 + gmt * 64;
      base[gqd0 * 16 + (gkl ^ (gqd0 * 2 + gkcl))]           = fr0;
      base[(gqd0 + 1) * 16 + (gkl ^ (gqd0 * 2 + 2 + gkcl))] = fr1;
    }
  };

  f32x4 zero4; zero4[0] = 0.f; zero4[1] = 0.f; zero4[2] = 0.f; zero4[3] = 0.f;

  __syncthreads();           // qe_s ready
  gen_load(0, 0);
  gen_store();
  __syncthreads();

  for (int q = 0; q < 2; q++) {
    f32x4 acc[2][7];
#pragma unroll
    for (int ct = 0; ct < 2; ct++)
#pragma unroll
      for (int mt = 0; mt < 7; mt++) acc[ct][mt] = zero4;

    for (int p = 0; p < 4; p++) {
      bool have_next = !(p == 3 && q == 1);
      int nq = (p == 3) ? q + 1 : q;
      int npair = (p == 3) ? 0 : p + 1;
      if (have_next) gen_load(nq, npair);   // loads in flight across MFMAs

      const bf16x8* pb = (const bf16x8*)smem;
#pragma unroll
      for (int kh2 = 0; kh2 < 2; kh2++) {
        int kc = p * 2 + kh2;
        bf16x8 pf[7];
#pragma unroll
        for (int mt = 0; mt < 7; mt++)
          pf[mt] = pb[kh2 * 448 + mt * 64 + quad * 16 + (l15 ^ (quad * 2 + kh2))];
#pragma unroll
        for (int mt = 0; mt < 7; mt++) {
          acc[0][mt] = __builtin_amdgcn_mfma_f32_16x16x32_bf16(wfrag[0][kc], pf[mt], acc[0][mt], 0, 0, 0);
          acc[1][mt] = __builtin_amdgcn_mfma_f32_16x16x32_bf16(wfrag[1][kc], pf[mt], acc[1][mt], 0, 0, 0);
        }
      }
      if (have_next) {
        __syncthreads();        // all reads of the buffer done
        gen_store();
        __syncthreads();        // new buffer visible
      }
    }

    // hid = relu(D1 + b1)  (lane: c=32w+ct*16+quad*4+r, key=mt*16+l15)
#pragma unroll
    for (int ct = 0; ct < 2; ct++)
#pragma unroll
      for (int mt = 0; mt < 7; mt++)
#pragma unroll
        for (int r = 0; r < 4; r++)
          acc[ct][mt][r] = fmaxf(acc[ct][mt][r] + b1v[ct][r], 0.0f);

    // GEMM2 exchange helpers
    auto wreg = [&](int mt, int slot) {
#pragma unroll
      for (int ct = 0; ct < 2; ct++) {
        int qt = ct * 2 + (quad >> 1);
        int j0 = (quad & 1) * 4;
        bf16x4 o;
#pragma unroll
        for (int r = 0; r < 4; r++) o[r] = (__bf16)acc[ct][mt][r];
        *(bf16x4*)(region + slot * 4096 + ((w * 64 + qt * 16 + l15) << 3) + j0) = o;
      }
    };
    auto g2 = [&](int qq, int mt, int slot) {
      f32x4 acc2 = zero4;
      const __bf16* rg = region + slot * 4096;
#pragma unroll
      for (int s = 0; s < 8; s++) {
        bf16x8 w2f = *(const bf16x8*)(w2pb + (unsigned)l15 * 256u + s * 32 + quad * 8);
        bf16x8 hf = *(const bf16x8*)(rg + (s * 64 + lane) * 8);
        acc2 = __builtin_amdgcn_mfma_f32_16x16x32_bf16(w2f, hf, acc2, 0, 0, 0);
      }
      if (quad < 2) {
        int key = mt * 16 + l15;
        if (key < 100) {
#pragma unroll
          for (int r = 0; r < 4; r++)
            bias_s[(qq * 8 + quad * 4 + r) * 104 + key] = (__bf16)(acc2[r] + b2v[r]);
        }
      }
    };

    wreg(0, 0); wreg(1, 1); wreg(2, 2); wreg(3, 3);
    __syncthreads();
    if (w < 4) g2(q, w, w);
    __syncthreads();
    wreg(4, 0); wreg(5, 1); wreg(6, 2);
    __syncthreads();
    if (w < 3) g2(q, 4 + w, w);
    __syncthreads();
  }

  // ================= phase 2: attention + epilogues =================
  // qh into LDS (overlays peA — all GEMM reads are behind barriers)
  {
    int q = t >> 8, c = t & 255;
    qh_s[q * 288 + (c >> 5) * 36 + (c & 31)] = (float)qhb[(unsigned)(q0 + q) * 256u + c];
  }
  __syncthreads();

  // scores = bias + qh.kh  (writes overlay the region area)
#pragma unroll
  for (int i = 0; i < 2; i++) {
    int p = t + i * 512;
    if (p < 800) {
      int k = p >> 3, h = p & 7;
      const float4* kf4 = (const float4*)(kh + (unsigned)(n * 100 + k) * 256u + h * 32);
      float4 kv[8];
#pragma unroll
      for (int dd = 0; dd < 8; dd++) kv[dd] = kf4[dd];
#pragma unroll
      for (int q = 0; q < 2; q++) {
        const float4* qf4 = (const float4*)(qh_s + q * 288 + h * 36);
        float s = (float)bias_s[(q * 8 + h) * 104 + k];
#pragma unroll
        for (int dd = 0; dd < 8; dd++) {
          float4 qv = qf4[dd];
          s += kv[dd].x * qv.x + kv[dd].y * qv.y + kv[dd].z * qv.z + kv[dd].w * qv.w;
        }
        scores[(q * 8 + h) * 104 + k] = s;
      }
    }
  }
  __syncthreads();

  // softmax: 16 rows (2q x 8h) x 32 lanes
  {
    int row = t >> 5, j = t & 31;
    float* rp = scores + row * 104;
    float mx = -1e30f;
    for (int k = j; k < 100; k += 32) mx = fmaxf(mx, rp[k]);
    mx = fmaxf(mx, __shfl_xor(mx, 1, 32));
    mx = fmaxf(mx, __shfl_xor(mx, 2, 32));
    mx = fmaxf(mx, __shfl_xor(mx, 4, 32));
    mx = fmaxf(mx, __shfl_xor(mx, 8, 32));
    mx = fmaxf(mx, __shfl_xor(mx, 16, 32));
    float sum = 0.f;
    for (int k = j; k < 100; k += 32) { float e = __expf(rp[k] - mx); rp[k] = e; sum += e; }
    sum += __shfl_xor(sum, 1, 32);
    sum += __shfl_xor(sum, 2, 32);
    sum += __shfl_xor(sum, 4, 32);
    sum += __shfl_xor(sum, 8, 32);
    sum += __shfl_xor(sum, 16, 32);
    float inv = 1.0f / sum;
    for (int k = j; k < 100; k += 32) rp[k] *= inv;
  }
  __syncthreads();

  // aw = mean over heads; ctx = attn @ vh
  if (t < 200) {
    int q = t / 100, k = t % 100;
    float s = 0.f;
#pragma unroll
    for (int h = 0; h < 8; h++) s += scores[(q * 8 + h) * 104 + k];
    aw_s[q * 104 + k] = s * 0.125f;
  }
  {
    int q = t >> 8, c = t & 255, h = c >> 5;
    float a = 0.f;
    const float* vp = vh + (unsigned)(n * 100) * 256u + c;
    const float* rw = scores + (q * 8 + h) * 104;
#pragma unroll 4
    for (int k = 0; k < 100; k++)
      a = fmaf(rw[k], vp[(unsigned)k * 256u], a);
    ctx_s[q * 256 + c] = a;
  }
  __syncthreads();

  // new_pos (cat extras)
  if (t < 4) {
    int q = t >> 1, cd = t & 1;
    float qp = qpos[(q0 + q) * 2 + cd];
    float s = 0.f;
    for (int k = 0; k < 100; k++)
      s = fmaf(aw_s[q * 104 + k], kpos[(n * 100 + k) * 2 + cd] - qp, s);
    float so = __shfl_xor(s, 1, 2);
    if (cd == 0) cat_s[q * 264 + 256] = ptw[0] * s + ptw[1] * so;
    else         cat_s[q * 264 + 257] = ptw[2] * so + ptw[3] * s;
  }

  // out_proj: thread handles (q = t>>8, c = t&255)
  {
    int q = t >> 8, c = t & 255;
    float a = out_b[c];
#pragma unroll
    for (int ch = 0; ch < 4; ch++) {
      float v0 = ctx_s[q * 256 + ch * 64 + lane];
      const __bf16* wp = owtb + (unsigned)(ch * 64) * 256u + c;
#pragma unroll 8
      for (int j2 = 0; j2 < 64; j2++)
        a = fmaf(rdlane(v0, j2), (float)wp[(unsigned)j2 * 256u], a);
    }
    cat_s[q * 264 + c] = fmaxf(qfeat[(unsigned)(q0 + q) * 256u + c] + a, 0.f);
  }
  __syncthreads();

  // embed (rows 256/257 = new_pos)
  {
    int q = t >> 8, c = t & 255;
    float a = embed_b[c];
#pragma unroll
    for (int ch = 0; ch < 4; ch++) {
      float v0 = cat_s[q * 264 + ch * 64 + lane];
      const __bf16* wp = ewtb + (unsigned)(ch * 64) * 256u + c;
#pragma unroll 8
      for (int j2 = 0; j2 < 64; j2++)
        a = fmaf(rdlane(v0, j2), (float)wp[(unsigned)j2 * 256u], a);
    }
    float w256 = (float)ewtb[256u * 256u + c];
    float w257 = (float)ewtb[257u * 256u + c];
    a += cat_s[q * 264 + 256] * w256 + cat_s[q * 264 + 257] * w257;
    out[(unsigned)(q0 + q) * 256u + c] = fmaxf(a, 0.f);
  }
}

// ---------------------------------------------------------------------------
extern "C" void kernel_launch(void* const* d_in, const int* in_sizes, int n_in,
                              void* d_out, int out_size, void* d_ws, size_t ws_size,
                              hipStream_t stream)
{
  const float* query_feature  = (const float*)d_in[0];
  const float* query_position = (const float*)d_in[1];
  const float* key_feature    = (const float*)d_in[2];
  const float* key_position   = (const float*)d_in[3];
  const float* in_proj_w      = (const float*)d_in[4];
  const float* in_proj_b      = (const float*)d_in[5];
  const float* out_proj_w     = (const float*)d_in[6];
  const float* out_proj_b     = (const float*)d_in[7];
  const float* pos_w1         = (const float*)d_in[8];
  const float* pos_b1         = (const float*)d_in[9];
  const float* pos_w2         = (const float*)d_in[10];
  const float* pos_b2         = (const float*)d_in[11];
  const float* pos_trans_w    = (const float*)d_in[12];
  const float* embed_w        = (const float*)d_in[13];
  const float* embed_b        = (const float*)d_in[14];
  float* ws  = (float*)d_ws;
  float* out = (float*)d_out;

  hipLaunchKernelGGL(prep1_kernel, dim3(199), dim3(256), 0, stream,
                     key_position, pos_w1, pos_w2, embed_w, out_proj_w,
                     in_proj_w, ws);
  hipLaunchKernelGGL(prep2_kernel, dim3(432), dim3(256), 0, stream,
                     query_feature, key_feature, in_proj_b, ws);
  hipLaunchKernelGGL(fused_kernel, dim3(1600), dim3(512), 0, stream,
                     query_position, key_position, query_feature,
                     pos_b1, pos_b2, out_proj_b, embed_b, pos_trans_w,
                     ws, out);
}